// Round 2
// baseline (138.388 us; speedup 1.0000x reference)
//
#include <hip/hip_runtime.h>

#define NCLS 10
#define NBLK 2048   // grid size of loss_main; partials are [2*NCLS][NBLK] in d_ws

// Column-major partials in d_ws: partial[c*NBLK + b]
//   c in [0,10)  : per-class sum of (o-t)^2 * m  for block b
//   c in [10,20) : per-class masked count (float) for block b
// Every slot is fully written by loss_main before loss_reduce reads it,
// so the harness's 0xAA poison of d_ws is harmless.
__global__ __launch_bounds__(256) void loss_main(const float* __restrict__ outputs,
                                                 const int* __restrict__ targets,
                                                 const int* __restrict__ mask,
                                                 float* __restrict__ partial,
                                                 int n) {
    float sum[NCLS];
    float cnt[NCLS];
#pragma unroll
    for (int c = 0; c < NCLS; ++c) { sum[c] = 0.0f; cnt[c] = 0.0f; }

    const int tid = blockIdx.x * blockDim.x + threadIdx.x;
    const int stride = gridDim.x * blockDim.x;
    const int nv = n >> 2;  // vec4 groups

    const float4* __restrict__ o4 = (const float4*)outputs;
    const int4*   __restrict__ t4 = (const int4*)targets;
    const int4*   __restrict__ m4 = (const int4*)mask;

    for (int i = tid; i < nv; i += stride) {
        float4 o = o4[i];
        int4   t = t4[i];
        int4   mk = m4[i];

        {
            float m = (mk.x == 1) ? 1.0f : 0.0f;
            float d = o.x - (float)t.x; d = d * d * m;
#pragma unroll
            for (int c = 0; c < NCLS; ++c) {
                bool hit = (t.x == c);
                sum[c] += hit ? d : 0.0f;
                cnt[c] += hit ? m : 0.0f;
            }
        }
        {
            float m = (mk.y == 1) ? 1.0f : 0.0f;
            float d = o.y - (float)t.y; d = d * d * m;
#pragma unroll
            for (int c = 0; c < NCLS; ++c) {
                bool hit = (t.y == c);
                sum[c] += hit ? d : 0.0f;
                cnt[c] += hit ? m : 0.0f;
            }
        }
        {
            float m = (mk.z == 1) ? 1.0f : 0.0f;
            float d = o.z - (float)t.z; d = d * d * m;
#pragma unroll
            for (int c = 0; c < NCLS; ++c) {
                bool hit = (t.z == c);
                sum[c] += hit ? d : 0.0f;
                cnt[c] += hit ? m : 0.0f;
            }
        }
        {
            float m = (mk.w == 1) ? 1.0f : 0.0f;
            float d = o.w - (float)t.w; d = d * d * m;
#pragma unroll
            for (int c = 0; c < NCLS; ++c) {
                bool hit = (t.w == c);
                sum[c] += hit ? d : 0.0f;
                cnt[c] += hit ? m : 0.0f;
            }
        }
    }

    // scalar tail (n % 4 != 0 — not expected at this shape, but safe)
    for (int i = (nv << 2) + tid; i < n; i += stride) {
        int t = targets[i];
        float m = (mask[i] == 1) ? 1.0f : 0.0f;
        float d = outputs[i] - (float)t; d = d * d * m;
#pragma unroll
        for (int c = 0; c < NCLS; ++c) {
            bool hit = (t == c);
            sum[c] += hit ? d : 0.0f;
            cnt[c] += hit ? m : 0.0f;
        }
    }

    // wave-64 butterfly reduction
#pragma unroll
    for (int c = 0; c < NCLS; ++c) {
#pragma unroll
        for (int off = 32; off > 0; off >>= 1) {
            sum[c] += __shfl_xor(sum[c], off, 64);
            cnt[c] += __shfl_xor(cnt[c], off, 64);
        }
    }

    __shared__ float sp[4][2 * NCLS];  // 4 waves per block
    const int lane = threadIdx.x & 63;
    const int wave = threadIdx.x >> 6;
    if (lane == 0) {
#pragma unroll
        for (int c = 0; c < NCLS; ++c) {
            sp[wave][c] = sum[c];
            sp[wave][NCLS + c] = cnt[c];
        }
    }
    __syncthreads();
    if (threadIdx.x < 2 * NCLS) {
        float v = sp[0][threadIdx.x] + sp[1][threadIdx.x] +
                  sp[2][threadIdx.x] + sp[3][threadIdx.x];
        partial[threadIdx.x * NBLK + blockIdx.x] = v;
    }
}

// One block, 16 waves. Wave w reduces columns {w, w+16} of partial (coalesced),
// then thread 0 finalizes:
//   out[0] = loss, out[1..10] = loss4each, out[11..20] = class_n
__global__ __launch_bounds__(1024) void loss_reduce(const float* __restrict__ partial,
                                                    float* __restrict__ out) {
    __shared__ float col[2 * NCLS];
    const int wave = threadIdx.x >> 6;
    const int lane = threadIdx.x & 63;

    for (int c = wave; c < 2 * NCLS; c += 16) {
        float v = 0.0f;
        for (int r = lane; r < NBLK; r += 64) v += partial[c * NBLK + r];
#pragma unroll
        for (int off = 32; off > 0; off >>= 1) v += __shfl_xor(v, off, 64);
        if (lane == 0) col[c] = v;
    }
    __syncthreads();

    if (threadIdx.x == 0) {
        float loss = 0.0f;
#pragma unroll
        for (int c = 0; c < NCLS; ++c) {
            float s = col[c];
            float nn = col[NCLS + c];
            float l4 = (nn > 0.0f) ? (s / nn) : 0.0f;  // nn>0 => nn>=1, matches max(nn,1)
            out[1 + c] = l4;
            out[11 + c] = nn;
            loss += 0.1f * l4;
        }
        out[0] = loss;
    }
}

extern "C" void kernel_launch(void* const* d_in, const int* in_sizes, int n_in,
                              void* d_out, int out_size, void* d_ws, size_t ws_size,
                              hipStream_t stream) {
    const float* outputs = (const float*)d_in[0];
    const int*   targets = (const int*)d_in[1];
    const int*   mask    = (const int*)d_in[2];
    float* out = (float*)d_out;
    float* partial = (float*)d_ws;   // needs 2*NCLS*NBLK*4 = 160 KB
    const int n = in_sizes[0];

    loss_main<<<NBLK, 256, 0, stream>>>(outputs, targets, mask, partial, n);
    loss_reduce<<<1, 1024, 0, stream>>>(partial, out);
}

// Round 4
// 123.682 us; speedup vs baseline: 1.1189x; 1.1189x over previous
//
#include <hip/hip_runtime.h>

#define NCLS 10
#define NBLK 1024   // grid size of loss_main; partials are [2*NCLS][NBLK] in d_ws

// Column-major partials in d_ws: partial[c*NBLK + b]
//   c in [0,10)  : per-class sum of (o-t)^2 * m  for block b
//   c in [10,20) : per-class masked count (float) for block b
// Every slot is fully written by loss_main before loss_reduce reads it,
// so the harness's 0xAA poison of d_ws is harmless.
__global__ __launch_bounds__(256) void loss_main(const float* __restrict__ outputs,
                                                 const int* __restrict__ targets,
                                                 const int* __restrict__ mask,
                                                 float* __restrict__ partial,
                                                 int n) {
    float sum[NCLS];
    float cnt[NCLS];
#pragma unroll
    for (int c = 0; c < NCLS; ++c) { sum[c] = 0.0f; cnt[c] = 0.0f; }

    const int tid = blockIdx.x * blockDim.x + threadIdx.x;
    const int stride = gridDim.x * blockDim.x;
    const int nv = n >> 2;  // vec4 groups

    const float4* __restrict__ o4 = (const float4*)outputs;
    const int4*   __restrict__ t4 = (const int4*)targets;
    const int4*   __restrict__ m4 = (const int4*)mask;

    for (int i = tid; i < nv; i += stride) {
        float4 o = o4[i];
        int4   t = t4[i];
        int4   mk = m4[i];

        {
            float m = (mk.x == 1) ? 1.0f : 0.0f;
            float d = o.x - (float)t.x; d = d * d * m;
#pragma unroll
            for (int c = 0; c < NCLS; ++c) {
                bool hit = (t.x == c);
                sum[c] += hit ? d : 0.0f;
                cnt[c] += hit ? m : 0.0f;
            }
        }
        {
            float m = (mk.y == 1) ? 1.0f : 0.0f;
            float d = o.y - (float)t.y; d = d * d * m;
#pragma unroll
            for (int c = 0; c < NCLS; ++c) {
                bool hit = (t.y == c);
                sum[c] += hit ? d : 0.0f;
                cnt[c] += hit ? m : 0.0f;
            }
        }
        {
            float m = (mk.z == 1) ? 1.0f : 0.0f;
            float d = o.z - (float)t.z; d = d * d * m;
#pragma unroll
            for (int c = 0; c < NCLS; ++c) {
                bool hit = (t.z == c);
                sum[c] += hit ? d : 0.0f;
                cnt[c] += hit ? m : 0.0f;
            }
        }
        {
            float m = (mk.w == 1) ? 1.0f : 0.0f;
            float d = o.w - (float)t.w; d = d * d * m;
#pragma unroll
            for (int c = 0; c < NCLS; ++c) {
                bool hit = (t.w == c);
                sum[c] += hit ? d : 0.0f;
                cnt[c] += hit ? m : 0.0f;
            }
        }
    }

    // scalar tail (n % 4 != 0 — not expected at this shape, but safe)
    for (int i = (nv << 2) + tid; i < n; i += stride) {
        int t = targets[i];
        float m = (mask[i] == 1) ? 1.0f : 0.0f;
        float d = outputs[i] - (float)t; d = d * d * m;
#pragma unroll
        for (int c = 0; c < NCLS; ++c) {
            bool hit = (t == c);
            sum[c] += hit ? d : 0.0f;
            cnt[c] += hit ? m : 0.0f;
        }
    }

    // wave-64 butterfly reduction of all 20 accumulators
#pragma unroll
    for (int c = 0; c < NCLS; ++c) {
#pragma unroll
        for (int off = 32; off > 0; off >>= 1) {
            sum[c] += __shfl_xor(sum[c], off, 64);
            cnt[c] += __shfl_xor(cnt[c], off, 64);
        }
    }

    __shared__ float sp[4][2 * NCLS];  // 4 waves per block
    const int lane = threadIdx.x & 63;
    const int wave = threadIdx.x >> 6;
    if (lane == 0) {
#pragma unroll
        for (int c = 0; c < NCLS; ++c) {
            sp[wave][c] = sum[c];
            sp[wave][NCLS + c] = cnt[c];
        }
    }
    __syncthreads();
    if (threadIdx.x < 2 * NCLS) {
        float v = sp[0][threadIdx.x] + sp[1][threadIdx.x] +
                  sp[2][threadIdx.x] + sp[3][threadIdx.x];
        partial[threadIdx.x * NBLK + blockIdx.x] = v;
    }
}

// One block, 16 waves. A column is NBLK=1024 floats = 256 float4s; each of the
// 64 lanes reads 4 float4s (lane, lane+64, lane+128, lane+192) -> 16 floats/lane.
// Wave w reduces columns {w, w+16}; thread 0 finalizes:
//   out[0] = loss, out[1..10] = loss4each, out[11..20] = class_n
__global__ __launch_bounds__(1024) void loss_reduce(const float* __restrict__ partial,
                                                    float* __restrict__ out) {
    __shared__ float col[2 * NCLS];
    const int wave = threadIdx.x >> 6;
    const int lane = threadIdx.x & 63;

#pragma unroll
    for (int k = 0; k < 2; ++k) {
        const int c = wave + k * 16;
        if (c < 2 * NCLS) {
            const float4* p4 = (const float4*)(partial + c * NBLK);
            float v = 0.0f;
#pragma unroll
            for (int j = 0; j < NBLK / 4 / 64; ++j) {   // 4 iterations
                float4 f = p4[lane + j * 64];
                v += (f.x + f.y) + (f.z + f.w);
            }
#pragma unroll
            for (int off = 32; off > 0; off >>= 1) v += __shfl_xor(v, off, 64);
            if (lane == 0) col[c] = v;
        }
    }
    __syncthreads();

    if (threadIdx.x == 0) {
        float loss = 0.0f;
#pragma unroll
        for (int c = 0; c < NCLS; ++c) {
            float s = col[c];
            float nn = col[NCLS + c];
            float l4 = (nn > 0.0f) ? (s / nn) : 0.0f;  // nn>0 => nn>=1, matches max(nn,1)
            out[1 + c] = l4;
            out[11 + c] = nn;
            loss += 0.1f * l4;
        }
        out[0] = loss;
    }
}

extern "C" void kernel_launch(void* const* d_in, const int* in_sizes, int n_in,
                              void* d_out, int out_size, void* d_ws, size_t ws_size,
                              hipStream_t stream) {
    const float* outputs = (const float*)d_in[0];
    const int*   targets = (const int*)d_in[1];
    const int*   mask    = (const int*)d_in[2];
    float* out = (float*)d_out;
    float* partial = (float*)d_ws;   // needs 2*NCLS*NBLK*4 = 80 KB
    const int n = in_sizes[0];

    loss_main<<<NBLK, 256, 0, stream>>>(outputs, targets, mask, partial, n);
    loss_reduce<<<1, 1024, 0, stream>>>(partial, out);
}